// Round 21
// baseline (176.011 us; speedup 1.0000x reference)
//
#include <hip/hip_runtime.h>
#include <math.h>

#define N 8192
#define FIN 129
#define D 64
#define TEMP 10.0f
#define LOG2E 1.4426950408889634f
#define SPLIT_S 32            // j-slices for stats passes (4 blk/CU, R18-validated)
#define SPLIT_W 32            // j-slices for write pass (4 blk/CU)
#define RG 4                  // row-groups per wave -> 64 rows/wave
#define BROWS 256             // 4 waves * 64 rows

typedef _Float16 f16x8 __attribute__((ext_vector_type(8)));
typedef float    f32x4 __attribute__((ext_vector_type(4)));

#define MFMA16(A, B, C) __builtin_amdgcn_mfma_f32_16x16x32_f16((A), (B), (C), 0, 0, 0)

// Raw v_exp_f32 (2^x). Safe here: |x| <~ 30 (no-shift softmax bound).
static __device__ inline float fast_exp2(float x) {
#if __has_builtin(__builtin_amdgcn_exp2f)
    return __builtin_amdgcn_exp2f(x);
#else
    float r; asm("v_exp_f32 %0, %1" : "=v"(r) : "v"(x)); return r;
#endif
}

// R18 kernels byte-identical (R20's SPLIT_S=64+lb8 reverted: regressed).
// TIMING PROBE: k_mlp and k_max each launched TWICE (idempotent).
// dur - 124.6 = t_mlp + t_max + ~2us gaps; sumL = 68 - that (R19).

// ---------------- Kernel 1: q = mlp_q(x), k = mlp_k(x) -> f16 ----------------
__global__ __launch_bounds__(256) void k_mlp(
    const float* __restrict__ x,
    const float* __restrict__ Wq1, const float* __restrict__ bq1,
    const float* __restrict__ Wq2, const float* __restrict__ bq2,
    const float* __restrict__ Wk1, const float* __restrict__ bk1,
    const float* __restrict__ Wk2, const float* __restrict__ bk2,
    _Float16* __restrict__ qo, _Float16* __restrict__ ko)
{
    __shared__ float xs[4][FIN];
    __shared__ float hqs[4][D];
    __shared__ float hks[4][D];
    const int wave = threadIdx.x >> 6;
    const int lane = threadIdx.x & 63;
    const int row  = (blockIdx.x << 2) + wave;

    const float* xr = x + row * FIN;
    xs[wave][lane]      = xr[lane];
    xs[wave][64 + lane] = xr[64 + lane];
    if (lane == 0) xs[wave][128] = xr[128];
    __syncthreads();

    float aq = bq1[lane], ak = bk1[lane];
    for (int f = 0; f < FIN; ++f) {
        const float xv = xs[wave][f];
        aq = fmaf(xv, Wq1[f * D + lane], aq);
        ak = fmaf(xv, Wk1[f * D + lane], ak);
    }
    hqs[wave][lane] = fmaxf(aq, 0.f);
    hks[wave][lane] = fmaxf(ak, 0.f);
    __syncthreads();

    float oq = bq2[lane], ok = bk2[lane];
    for (int t = 0; t < D; ++t) {
        oq = fmaf(hqs[wave][t], Wq2[t * D + lane], oq);
        ok = fmaf(hks[wave][t], Wk2[t * D + lane], ok);
    }
    qo[row * D + lane] = (_Float16)oq;
    ko[row * D + lane] = (_Float16)ok;
}

// ---------------- Pass 1: raw row max -> mpart[SPLIT_S][N] (pipelined) ----------------
__global__ __launch_bounds__(256) void k_max(
    const _Float16* __restrict__ q16, const _Float16* __restrict__ k16,
    float* __restrict__ mpart)
{
    const int tid  = threadIdx.x;
    const int wave = tid >> 6;
    const int lane = tid & 63;
    const int lr   = lane & 15;
    const int lg   = lane >> 4;
    const int i0   = blockIdx.x * BROWS + wave * 64;
    const int jbase = blockIdx.y * (N / SPLIT_S);
    const int S = (N / SPLIT_S) / 16;      // 16 sub-steps of 16 k-rows

    f16x8 b[RG][2];
    #pragma unroll
    for (int rg = 0; rg < RG; ++rg) {
        b[rg][0] = *reinterpret_cast<const f16x8*>(&q16[(i0 + rg * 16 + lr) * D + 8 * lg]);
        b[rg][1] = *reinterpret_cast<const f16x8*>(&q16[(i0 + rg * 16 + lr) * D + 32 + 8 * lg]);
    }

    float mx[RG];
    #pragma unroll
    for (int rg = 0; rg < RG; ++rg) mx[rg] = -INFINITY;

    f16x8 a0[2], a1[2];
    a0[0] = *reinterpret_cast<const f16x8*>(&k16[(jbase + lr) * D + 8 * lg]);
    a1[0] = *reinterpret_cast<const f16x8*>(&k16[(jbase + lr) * D + 32 + 8 * lg]);

    #pragma unroll
    for (int s = 0; s < 16; ++s) {
        const int p = s & 1;
        if (s + 1 < S) {
            const int jr = jbase + (s + 1) * 16;
            a0[1 - p] = *reinterpret_cast<const f16x8*>(&k16[(jr + lr) * D + 8 * lg]);
            a1[1 - p] = *reinterpret_cast<const f16x8*>(&k16[(jr + lr) * D + 32 + 8 * lg]);
        }
        #pragma unroll
        for (int rg = 0; rg < RG; ++rg) {
            f32x4 acc = {0.f, 0.f, 0.f, 0.f};
            acc = MFMA16(a0[p], b[rg][0], acc);
            acc = MFMA16(a1[p], b[rg][1], acc);
            mx[rg] = fmaxf(mx[rg], fmaxf(fmaxf(acc[0], acc[1]), fmaxf(acc[2], acc[3])));
        }
    }

    #pragma unroll
    for (int rg = 0; rg < RG; ++rg) {
        mx[rg] = fmaxf(mx[rg], __shfl_xor(mx[rg], 16));
        mx[rg] = fmaxf(mx[rg], __shfl_xor(mx[rg], 32));
    }
    if (lane < 16) {
        #pragma unroll
        for (int rg = 0; rg < RG; ++rg)
            mpart[blockIdx.y * N + i0 + rg * 16 + lr] = mx[rg];
    }
}

// ---------------- Pass 2: Lpart[s][i] = sum_j exp2(s2_ij); rinv from LDS prologue ----------------
__global__ __launch_bounds__(256) void k_sumL(
    const _Float16* __restrict__ q16, const _Float16* __restrict__ k16,
    const float* __restrict__ mpart, float* __restrict__ Lpart)
{
    const int tid  = threadIdx.x;
    const int wave = tid >> 6;
    const int lane = tid & 63;
    const int lr   = lane & 15;
    const int lg   = lane >> 4;
    const int i0   = blockIdx.x * BROWS + wave * 64;
    const int jbase = blockIdx.y * (N / SPLIT_S);

    __shared__ float rinv_s[N / SPLIT_S];   // 256 cols per slice
    {
        float m = mpart[jbase + tid];
        #pragma unroll
        for (int s = 1; s < SPLIT_S; ++s) m = fmaxf(m, mpart[s * N + jbase + tid]);
        rinv_s[tid] = TEMP * LOG2E / m;
    }

    f16x8 b[RG][2];
    #pragma unroll
    for (int rg = 0; rg < RG; ++rg) {
        b[rg][0] = *reinterpret_cast<const f16x8*>(&q16[(i0 + rg * 16 + lr) * D + 8 * lg]);
        b[rg][1] = *reinterpret_cast<const f16x8*>(&q16[(i0 + rg * 16 + lr) * D + 32 + 8 * lg]);
    }
    __syncthreads();

    float sm[RG];
    #pragma unroll
    for (int rg = 0; rg < RG; ++rg) sm[rg] = 0.f;

    f16x8 a0[2], a1[2];
    a0[0] = *reinterpret_cast<const f16x8*>(&k16[(jbase + lr) * D + 8 * lg]);
    a1[0] = *reinterpret_cast<const f16x8*>(&k16[(jbase + lr) * D + 32 + 8 * lg]);

    #pragma unroll
    for (int s = 0; s < 16; ++s) {
        const int p = s & 1;
        if (s + 1 < 16) {
            const int jr = jbase + (s + 1) * 16;
            a0[1 - p] = *reinterpret_cast<const f16x8*>(&k16[(jr + lr) * D + 8 * lg]);
            a1[1 - p] = *reinterpret_cast<const f16x8*>(&k16[(jr + lr) * D + 32 + 8 * lg]);
        }
        const float4 r4 = *reinterpret_cast<const float4*>(&rinv_s[s * 16 + lg * 4]);
        #pragma unroll
        for (int rg = 0; rg < RG; ++rg) {
            f32x4 acc = {0.f, 0.f, 0.f, 0.f};
            acc = MFMA16(a0[p], b[rg][0], acc);
            acc = MFMA16(a1[p], b[rg][1], acc);
            sm[rg] += fast_exp2(acc[0] * r4.x) + fast_exp2(acc[1] * r4.y)
                    + fast_exp2(acc[2] * r4.z) + fast_exp2(acc[3] * r4.w);
        }
    }

    #pragma unroll
    for (int rg = 0; rg < RG; ++rg) {
        sm[rg] += __shfl_xor(sm[rg], 16);
        sm[rg] += __shfl_xor(sm[rg], 32);
    }
    if (lane < 16) {
        #pragma unroll
        for (int rg = 0; rg < RG; ++rg)
            Lpart[blockIdx.y * N + i0 + rg * 16 + lr] = sm[rg];
    }
}

// ---------------- Pass 3: paired line-completing PLAIN stores ----------------
__global__ __launch_bounds__(256) void k_write(
    const _Float16* __restrict__ q16, const _Float16* __restrict__ k16,
    const float* __restrict__ mpart, const float* __restrict__ Lpart,
    float* __restrict__ out)
{
    const int tid  = threadIdx.x;
    const int wave = tid >> 6;
    const int lane = tid & 63;
    const int lr   = lane & 15;
    const int lg   = lane >> 4;
    const int i0b  = blockIdx.x * BROWS;
    const int i0   = i0b + wave * 64;
    const int jbase = blockIdx.y * (N / SPLIT_W);

    __shared__ float rinv_s[N / SPLIT_W];   // 256 cols per slice
    __shared__ float linv_s[BROWS];         // 256 rows per block
    {
        float m = mpart[jbase + tid];
        #pragma unroll
        for (int s = 1; s < SPLIT_S; ++s) m = fmaxf(m, mpart[s * N + jbase + tid]);
        rinv_s[tid] = TEMP * LOG2E / m;
        float L = Lpart[i0b + tid];
        #pragma unroll
        for (int s = 1; s < SPLIT_S; ++s) L += Lpart[s * N + i0b + tid];
        linv_s[tid] = 1.f / L;
    }

    f16x8 b[RG][2];
    #pragma unroll
    for (int rg = 0; rg < RG; ++rg) {
        b[rg][0] = *reinterpret_cast<const f16x8*>(&q16[(i0 + rg * 16 + lr) * D + 8 * lg]);
        b[rg][1] = *reinterpret_cast<const f16x8*>(&q16[(i0 + rg * 16 + lr) * D + 32 + 8 * lg]);
    }
    __syncthreads();

    float Lvi[RG];
    #pragma unroll
    for (int rg = 0; rg < RG; ++rg) Lvi[rg] = linv_s[wave * 64 + rg * 16 + lr];

    // pair loop: 8 pairs x 32 cols; a[buf][0,1]=sub0 frags, a[buf][2,3]=sub1 frags
    f16x8 a[2][4];
    a[0][0] = *reinterpret_cast<const f16x8*>(&k16[(jbase + lr) * D + 8 * lg]);
    a[0][1] = *reinterpret_cast<const f16x8*>(&k16[(jbase + lr) * D + 32 + 8 * lg]);
    a[0][2] = *reinterpret_cast<const f16x8*>(&k16[(jbase + 16 + lr) * D + 8 * lg]);
    a[0][3] = *reinterpret_cast<const f16x8*>(&k16[(jbase + 16 + lr) * D + 32 + 8 * lg]);

    #pragma unroll
    for (int s2 = 0; s2 < 8; ++s2) {
        const int p = s2 & 1;
        if (s2 + 1 < 8) {
            const int jn = jbase + (s2 + 1) * 32;
            a[1 - p][0] = *reinterpret_cast<const f16x8*>(&k16[(jn + lr) * D + 8 * lg]);
            a[1 - p][1] = *reinterpret_cast<const f16x8*>(&k16[(jn + lr) * D + 32 + 8 * lg]);
            a[1 - p][2] = *reinterpret_cast<const f16x8*>(&k16[(jn + 16 + lr) * D + 8 * lg]);
            a[1 - p][3] = *reinterpret_cast<const f16x8*>(&k16[(jn + 16 + lr) * D + 32 + 8 * lg]);
        }
        const int j0 = jbase + s2 * 32;
        const float4 r40 = *reinterpret_cast<const float4*>(&rinv_s[s2 * 32 + lg * 4]);
        const float4 r41 = *reinterpret_cast<const float4*>(&rinv_s[s2 * 32 + 16 + lg * 4]);
        #pragma unroll
        for (int rg = 0; rg < RG; ++rg) {
            f32x4 acc0 = {0.f, 0.f, 0.f, 0.f};
            acc0 = MFMA16(a[p][0], b[rg][0], acc0);
            acc0 = MFMA16(a[p][1], b[rg][1], acc0);
            f32x4 acc1 = {0.f, 0.f, 0.f, 0.f};
            acc1 = MFMA16(a[p][2], b[rg][0], acc1);
            acc1 = MFMA16(a[p][3], b[rg][1], acc1);
            float4 o0, o1;
            o0.x = fast_exp2(acc0[0] * r40.x) * Lvi[rg];
            o0.y = fast_exp2(acc0[1] * r40.y) * Lvi[rg];
            o0.z = fast_exp2(acc0[2] * r40.z) * Lvi[rg];
            o0.w = fast_exp2(acc0[3] * r40.w) * Lvi[rg];
            o1.x = fast_exp2(acc1[0] * r41.x) * Lvi[rg];
            o1.y = fast_exp2(acc1[1] * r41.y) * Lvi[rg];
            o1.z = fast_exp2(acc1[2] * r41.z) * Lvi[rg];
            o1.w = fast_exp2(acc1[3] * r41.w) * Lvi[rg];
            float* rowp = out + (size_t)(i0 + rg * 16 + lr) * N + j0;
            // back-to-back stores complete the 128B line (cols j0..j0+31)
            *reinterpret_cast<float4*>(rowp + lg * 4)      = o0;
            *reinterpret_cast<float4*>(rowp + 16 + lg * 4) = o1;
        }
    }
}

extern "C" void kernel_launch(void* const* d_in, const int* in_sizes, int n_in,
                              void* d_out, int out_size, void* d_ws, size_t ws_size,
                              hipStream_t stream)
{
    const float* x   = (const float*)d_in[0];
    const float* Wq1 = (const float*)d_in[1];
    const float* bq1 = (const float*)d_in[2];
    const float* Wq2 = (const float*)d_in[3];
    const float* bq2 = (const float*)d_in[4];
    const float* Wk1 = (const float*)d_in[5];
    const float* bk1 = (const float*)d_in[6];
    const float* Wk2 = (const float*)d_in[7];
    const float* bk2 = (const float*)d_in[8];

    float* out = (float*)d_out;

    _Float16* q16 = (_Float16*)d_ws;                       // 1 MB
    _Float16* k16 = q16 + (size_t)N * D;                   // 1 MB
    float* mpart  = (float*)(k16 + (size_t)N * D);         // SPLIT_S*N
    float* Lpart  = mpart + (size_t)SPLIT_S * N;           // SPLIT_S*N

    // TIMING PROBE: k_mlp and k_max launched twice (idempotent).
    // dur - 124.6 (R18) = t_mlp + t_max + ~2us gaps.
    k_mlp  <<<N / 4, 256, 0, stream>>>(x, Wq1, bq1, Wq2, bq2, Wk1, bk1, Wk2, bk2, q16, k16);
    k_mlp  <<<N / 4, 256, 0, stream>>>(x, Wq1, bq1, Wq2, bq2, Wk1, bk1, Wk2, bk2, q16, k16);
    k_max  <<<dim3(N / BROWS, SPLIT_S), 256, 0, stream>>>(q16, k16, mpart);
    k_max  <<<dim3(N / BROWS, SPLIT_S), 256, 0, stream>>>(q16, k16, mpart);
    k_sumL <<<dim3(N / BROWS, SPLIT_S), 256, 0, stream>>>(q16, k16, mpart, Lpart);
    k_write<<<dim3(N / BROWS, SPLIT_W), 256, 0, stream>>>(q16, k16, mpart, Lpart, out);
}

// Round 22
// 120.363 us; speedup vs baseline: 1.4623x; 1.4623x over previous
//
#include <hip/hip_runtime.h>
#include <math.h>

#define N 8192
#define FIN 129
#define D 64
#define TEMP 10.0f
#define LOG2E 1.4426950408889634f
#define SPLIT_S 32            // j-slices for stats passes (4 blk/CU, R18-validated)
#define SPLIT_W 32            // j-slices for write pass (4 blk/CU)
#define RG 4                  // row-groups per wave -> 64 rows/wave
#define BROWS 256             // 4 waves * 64 rows
#define MROWS 4               // mlp: rows per wave (weight-traffic / ILP lever)

typedef _Float16 f16x8 __attribute__((ext_vector_type(8)));
typedef float    f32x4 __attribute__((ext_vector_type(4)));

#define MFMA16(A, B, C) __builtin_amdgcn_mfma_f32_16x16x32_f16((A), (B), (C), 0, 0, 0)

// Raw v_exp_f32 (2^x). Safe here: |x| <~ 30 (no-shift softmax bound).
static __device__ inline float fast_exp2(float x) {
#if __has_builtin(__builtin_amdgcn_exp2f)
    return __builtin_amdgcn_exp2f(x);
#else
    float r; asm("v_exp_f32 %0, %1" : "=v"(r) : "v"(x)); return r;
#endif
}

// Geometry (validated): B-frag q row i = i0+rg*16+lr; A-frag k row j = jr+lr;
// C elem e: col j = jr+lg*4+e. No-shift softmax (|s2|<~30).
// k_mlp v2: MROWS=4 rows/wave -> weight L2 traffic /4 (540->135MB), 8 indep
// FMA chains/lane. Per-row op order unchanged -> q16/k16 bitwise identical.

// ---------------- Kernel 1: q = mlp_q(x), k = mlp_k(x) -> f16 ----------------
__global__ __launch_bounds__(256) void k_mlp(
    const float* __restrict__ x,
    const float* __restrict__ Wq1, const float* __restrict__ bq1,
    const float* __restrict__ Wq2, const float* __restrict__ bq2,
    const float* __restrict__ Wk1, const float* __restrict__ bk1,
    const float* __restrict__ Wk2, const float* __restrict__ bk2,
    _Float16* __restrict__ qo, _Float16* __restrict__ ko)
{
    __shared__ float xs[4][MROWS][FIN];
    __shared__ float hqs[4][MROWS][D];
    __shared__ float hks[4][MROWS][D];
    const int wave  = threadIdx.x >> 6;
    const int lane  = threadIdx.x & 63;
    const int rbase = (blockIdx.x * 4 + wave) * MROWS;

    #pragma unroll
    for (int r = 0; r < MROWS; ++r) {
        const float* xr = x + (size_t)(rbase + r) * FIN;
        xs[wave][r][lane]      = xr[lane];
        xs[wave][r][64 + lane] = xr[64 + lane];
        if (lane == 0) xs[wave][r][128] = xr[128];
    }
    __syncthreads();

    float aq[MROWS], ak[MROWS];
    #pragma unroll
    for (int r = 0; r < MROWS; ++r) { aq[r] = bq1[lane]; ak[r] = bk1[lane]; }
    for (int f = 0; f < FIN; ++f) {
        const float wq = Wq1[f * D + lane];
        const float wk = Wk1[f * D + lane];
        #pragma unroll
        for (int r = 0; r < MROWS; ++r) {
            const float xv = xs[wave][r][f];
            aq[r] = fmaf(xv, wq, aq[r]);
            ak[r] = fmaf(xv, wk, ak[r]);
        }
    }
    #pragma unroll
    for (int r = 0; r < MROWS; ++r) {
        hqs[wave][r][lane] = fmaxf(aq[r], 0.f);
        hks[wave][r][lane] = fmaxf(ak[r], 0.f);
    }
    __syncthreads();

    float oq[MROWS], ok[MROWS];
    #pragma unroll
    for (int r = 0; r < MROWS; ++r) { oq[r] = bq2[lane]; ok[r] = bk2[lane]; }
    for (int t = 0; t < D; ++t) {
        const float wq2 = Wq2[t * D + lane];
        const float wk2 = Wk2[t * D + lane];
        #pragma unroll
        for (int r = 0; r < MROWS; ++r) {
            oq[r] = fmaf(hqs[wave][r][t], wq2, oq[r]);
            ok[r] = fmaf(hks[wave][r][t], wk2, ok[r]);
        }
    }
    #pragma unroll
    for (int r = 0; r < MROWS; ++r) {
        qo[(size_t)(rbase + r) * D + lane] = (_Float16)oq[r];
        ko[(size_t)(rbase + r) * D + lane] = (_Float16)ok[r];
    }
}

// ---------------- Pass 1: raw row max -> mpart[SPLIT_S][N] (pipelined) ----------------
__global__ __launch_bounds__(256) void k_max(
    const _Float16* __restrict__ q16, const _Float16* __restrict__ k16,
    float* __restrict__ mpart)
{
    const int tid  = threadIdx.x;
    const int wave = tid >> 6;
    const int lane = tid & 63;
    const int lr   = lane & 15;
    const int lg   = lane >> 4;
    const int i0   = blockIdx.x * BROWS + wave * 64;
    const int jbase = blockIdx.y * (N / SPLIT_S);
    const int S = (N / SPLIT_S) / 16;      // 16 sub-steps of 16 k-rows

    f16x8 b[RG][2];
    #pragma unroll
    for (int rg = 0; rg < RG; ++rg) {
        b[rg][0] = *reinterpret_cast<const f16x8*>(&q16[(i0 + rg * 16 + lr) * D + 8 * lg]);
        b[rg][1] = *reinterpret_cast<const f16x8*>(&q16[(i0 + rg * 16 + lr) * D + 32 + 8 * lg]);
    }

    float mx[RG];
    #pragma unroll
    for (int rg = 0; rg < RG; ++rg) mx[rg] = -INFINITY;

    f16x8 a0[2], a1[2];
    a0[0] = *reinterpret_cast<const f16x8*>(&k16[(jbase + lr) * D + 8 * lg]);
    a1[0] = *reinterpret_cast<const f16x8*>(&k16[(jbase + lr) * D + 32 + 8 * lg]);

    #pragma unroll
    for (int s = 0; s < 16; ++s) {
        const int p = s & 1;
        if (s + 1 < S) {
            const int jr = jbase + (s + 1) * 16;
            a0[1 - p] = *reinterpret_cast<const f16x8*>(&k16[(jr + lr) * D + 8 * lg]);
            a1[1 - p] = *reinterpret_cast<const f16x8*>(&k16[(jr + lr) * D + 32 + 8 * lg]);
        }
        #pragma unroll
        for (int rg = 0; rg < RG; ++rg) {
            f32x4 acc = {0.f, 0.f, 0.f, 0.f};
            acc = MFMA16(a0[p], b[rg][0], acc);
            acc = MFMA16(a1[p], b[rg][1], acc);
            mx[rg] = fmaxf(mx[rg], fmaxf(fmaxf(acc[0], acc[1]), fmaxf(acc[2], acc[3])));
        }
    }

    #pragma unroll
    for (int rg = 0; rg < RG; ++rg) {
        mx[rg] = fmaxf(mx[rg], __shfl_xor(mx[rg], 16));
        mx[rg] = fmaxf(mx[rg], __shfl_xor(mx[rg], 32));
    }
    if (lane < 16) {
        #pragma unroll
        for (int rg = 0; rg < RG; ++rg)
            mpart[blockIdx.y * N + i0 + rg * 16 + lr] = mx[rg];
    }
}

// ---------------- Pass 2: Lpart[s][i] = sum_j exp2(s2_ij); rinv from LDS prologue ----------------
__global__ __launch_bounds__(256) void k_sumL(
    const _Float16* __restrict__ q16, const _Float16* __restrict__ k16,
    const float* __restrict__ mpart, float* __restrict__ Lpart)
{
    const int tid  = threadIdx.x;
    const int wave = tid >> 6;
    const int lane = tid & 63;
    const int lr   = lane & 15;
    const int lg   = lane >> 4;
    const int i0   = blockIdx.x * BROWS + wave * 64;
    const int jbase = blockIdx.y * (N / SPLIT_S);

    __shared__ float rinv_s[N / SPLIT_S];   // 256 cols per slice
    {
        float m = mpart[jbase + tid];
        #pragma unroll
        for (int s = 1; s < SPLIT_S; ++s) m = fmaxf(m, mpart[s * N + jbase + tid]);
        rinv_s[tid] = TEMP * LOG2E / m;
    }

    f16x8 b[RG][2];
    #pragma unroll
    for (int rg = 0; rg < RG; ++rg) {
        b[rg][0] = *reinterpret_cast<const f16x8*>(&q16[(i0 + rg * 16 + lr) * D + 8 * lg]);
        b[rg][1] = *reinterpret_cast<const f16x8*>(&q16[(i0 + rg * 16 + lr) * D + 32 + 8 * lg]);
    }
    __syncthreads();

    float sm[RG];
    #pragma unroll
    for (int rg = 0; rg < RG; ++rg) sm[rg] = 0.f;

    f16x8 a0[2], a1[2];
    a0[0] = *reinterpret_cast<const f16x8*>(&k16[(jbase + lr) * D + 8 * lg]);
    a1[0] = *reinterpret_cast<const f16x8*>(&k16[(jbase + lr) * D + 32 + 8 * lg]);

    #pragma unroll
    for (int s = 0; s < 16; ++s) {
        const int p = s & 1;
        if (s + 1 < 16) {
            const int jr = jbase + (s + 1) * 16;
            a0[1 - p] = *reinterpret_cast<const f16x8*>(&k16[(jr + lr) * D + 8 * lg]);
            a1[1 - p] = *reinterpret_cast<const f16x8*>(&k16[(jr + lr) * D + 32 + 8 * lg]);
        }
        const float4 r4 = *reinterpret_cast<const float4*>(&rinv_s[s * 16 + lg * 4]);
        #pragma unroll
        for (int rg = 0; rg < RG; ++rg) {
            f32x4 acc = {0.f, 0.f, 0.f, 0.f};
            acc = MFMA16(a0[p], b[rg][0], acc);
            acc = MFMA16(a1[p], b[rg][1], acc);
            sm[rg] += fast_exp2(acc[0] * r4.x) + fast_exp2(acc[1] * r4.y)
                    + fast_exp2(acc[2] * r4.z) + fast_exp2(acc[3] * r4.w);
        }
    }

    #pragma unroll
    for (int rg = 0; rg < RG; ++rg) {
        sm[rg] += __shfl_xor(sm[rg], 16);
        sm[rg] += __shfl_xor(sm[rg], 32);
    }
    if (lane < 16) {
        #pragma unroll
        for (int rg = 0; rg < RG; ++rg)
            Lpart[blockIdx.y * N + i0 + rg * 16 + lr] = sm[rg];
    }
}

// ---------------- Pass 3: paired line-completing PLAIN stores ----------------
__global__ __launch_bounds__(256) void k_write(
    const _Float16* __restrict__ q16, const _Float16* __restrict__ k16,
    const float* __restrict__ mpart, const float* __restrict__ Lpart,
    float* __restrict__ out)
{
    const int tid  = threadIdx.x;
    const int wave = tid >> 6;
    const int lane = tid & 63;
    const int lr   = lane & 15;
    const int lg   = lane >> 4;
    const int i0b  = blockIdx.x * BROWS;
    const int i0   = i0b + wave * 64;
    const int jbase = blockIdx.y * (N / SPLIT_W);

    __shared__ float rinv_s[N / SPLIT_W];   // 256 cols per slice
    __shared__ float linv_s[BROWS];         // 256 rows per block
    {
        float m = mpart[jbase + tid];
        #pragma unroll
        for (int s = 1; s < SPLIT_S; ++s) m = fmaxf(m, mpart[s * N + jbase + tid]);
        rinv_s[tid] = TEMP * LOG2E / m;
        float L = Lpart[i0b + tid];
        #pragma unroll
        for (int s = 1; s < SPLIT_S; ++s) L += Lpart[s * N + i0b + tid];
        linv_s[tid] = 1.f / L;
    }

    f16x8 b[RG][2];
    #pragma unroll
    for (int rg = 0; rg < RG; ++rg) {
        b[rg][0] = *reinterpret_cast<const f16x8*>(&q16[(i0 + rg * 16 + lr) * D + 8 * lg]);
        b[rg][1] = *reinterpret_cast<const f16x8*>(&q16[(i0 + rg * 16 + lr) * D + 32 + 8 * lg]);
    }
    __syncthreads();

    float Lvi[RG];
    #pragma unroll
    for (int rg = 0; rg < RG; ++rg) Lvi[rg] = linv_s[wave * 64 + rg * 16 + lr];

    // pair loop: 8 pairs x 32 cols; a[buf][0,1]=sub0 frags, a[buf][2,3]=sub1 frags
    f16x8 a[2][4];
    a[0][0] = *reinterpret_cast<const f16x8*>(&k16[(jbase + lr) * D + 8 * lg]);
    a[0][1] = *reinterpret_cast<const f16x8*>(&k16[(jbase + lr) * D + 32 + 8 * lg]);
    a[0][2] = *reinterpret_cast<const f16x8*>(&k16[(jbase + 16 + lr) * D + 8 * lg]);
    a[0][3] = *reinterpret_cast<const f16x8*>(&k16[(jbase + 16 + lr) * D + 32 + 8 * lg]);

    #pragma unroll
    for (int s2 = 0; s2 < 8; ++s2) {
        const int p = s2 & 1;
        if (s2 + 1 < 8) {
            const int jn = jbase + (s2 + 1) * 32;
            a[1 - p][0] = *reinterpret_cast<const f16x8*>(&k16[(jn + lr) * D + 8 * lg]);
            a[1 - p][1] = *reinterpret_cast<const f16x8*>(&k16[(jn + lr) * D + 32 + 8 * lg]);
            a[1 - p][2] = *reinterpret_cast<const f16x8*>(&k16[(jn + 16 + lr) * D + 8 * lg]);
            a[1 - p][3] = *reinterpret_cast<const f16x8*>(&k16[(jn + 16 + lr) * D + 32 + 8 * lg]);
        }
        const int j0 = jbase + s2 * 32;
        const float4 r40 = *reinterpret_cast<const float4*>(&rinv_s[s2 * 32 + lg * 4]);
        const float4 r41 = *reinterpret_cast<const float4*>(&rinv_s[s2 * 32 + 16 + lg * 4]);
        #pragma unroll
        for (int rg = 0; rg < RG; ++rg) {
            f32x4 acc0 = {0.f, 0.f, 0.f, 0.f};
            acc0 = MFMA16(a[p][0], b[rg][0], acc0);
            acc0 = MFMA16(a[p][1], b[rg][1], acc0);
            f32x4 acc1 = {0.f, 0.f, 0.f, 0.f};
            acc1 = MFMA16(a[p][2], b[rg][0], acc1);
            acc1 = MFMA16(a[p][3], b[rg][1], acc1);
            float4 o0, o1;
            o0.x = fast_exp2(acc0[0] * r40.x) * Lvi[rg];
            o0.y = fast_exp2(acc0[1] * r40.y) * Lvi[rg];
            o0.z = fast_exp2(acc0[2] * r40.z) * Lvi[rg];
            o0.w = fast_exp2(acc0[3] * r40.w) * Lvi[rg];
            o1.x = fast_exp2(acc1[0] * r41.x) * Lvi[rg];
            o1.y = fast_exp2(acc1[1] * r41.y) * Lvi[rg];
            o1.z = fast_exp2(acc1[2] * r41.z) * Lvi[rg];
            o1.w = fast_exp2(acc1[3] * r41.w) * Lvi[rg];
            float* rowp = out + (size_t)(i0 + rg * 16 + lr) * N + j0;
            // back-to-back stores complete the 128B line (cols j0..j0+31)
            *reinterpret_cast<float4*>(rowp + lg * 4)      = o0;
            *reinterpret_cast<float4*>(rowp + 16 + lg * 4) = o1;
        }
    }
}

extern "C" void kernel_launch(void* const* d_in, const int* in_sizes, int n_in,
                              void* d_out, int out_size, void* d_ws, size_t ws_size,
                              hipStream_t stream)
{
    const float* x   = (const float*)d_in[0];
    const float* Wq1 = (const float*)d_in[1];
    const float* bq1 = (const float*)d_in[2];
    const float* Wq2 = (const float*)d_in[3];
    const float* bq2 = (const float*)d_in[4];
    const float* Wk1 = (const float*)d_in[5];
    const float* bk1 = (const float*)d_in[6];
    const float* Wk2 = (const float*)d_in[7];
    const float* bk2 = (const float*)d_in[8];

    float* out = (float*)d_out;

    _Float16* q16 = (_Float16*)d_ws;                       // 1 MB
    _Float16* k16 = q16 + (size_t)N * D;                   // 1 MB
    float* mpart  = (float*)(k16 + (size_t)N * D);         // SPLIT_S*N
    float* Lpart  = mpart + (size_t)SPLIT_S * N;           // SPLIT_S*N

    k_mlp  <<<N / (4 * MROWS), 256, 0, stream>>>(x, Wq1, bq1, Wq2, bq2, Wk1, bk1, Wk2, bk2, q16, k16);
    k_max  <<<dim3(N / BROWS, SPLIT_S), 256, 0, stream>>>(q16, k16, mpart);
    k_sumL <<<dim3(N / BROWS, SPLIT_S), 256, 0, stream>>>(q16, k16, mpart, Lpart);
    k_write<<<dim3(N / BROWS, SPLIT_W), 256, 0, stream>>>(q16, k16, mpart, Lpart, out);
}

// Round 23
// 117.423 us; speedup vs baseline: 1.4989x; 1.0250x over previous
//
#include <hip/hip_runtime.h>
#include <math.h>

#define N 8192
#define FIN 129
#define D 64
#define TEMP 10.0f
#define LOG2E 1.4426950408889634f
#define SPLIT_S 32            // j-slices for stats passes (4 blk/CU, R18-validated)
#define SPLIT_W 32            // j-slices for write pass (4 blk/CU)
#define RG 4                  // row-groups per wave -> 64 rows/wave
#define BROWS 256             // 4 waves * 64 rows
#define MROWS 2               // mlp: rows per wave (traffic/2, 16 waves/CU)

typedef _Float16 f16x8 __attribute__((ext_vector_type(8)));
typedef float    f32x4 __attribute__((ext_vector_type(4)));

#define MFMA16(A, B, C) __builtin_amdgcn_mfma_f32_16x16x32_f16((A), (B), (C), 0, 0, 0)

// Raw v_exp_f32 (2^x). Safe here: |x| <~ 30 (no-shift softmax bound).
static __device__ inline float fast_exp2(float x) {
#if __has_builtin(__builtin_amdgcn_exp2f)
    return __builtin_amdgcn_exp2f(x);
#else
    float r; asm("v_exp_f32 %0, %1" : "=v"(r) : "v"(x)); return r;
#endif
}

// Geometry (validated): B-frag q row i = i0+rg*16+lr; A-frag k row j = jr+lr;
// C elem e: col j = jr+lg*4+e. No-shift softmax (|s2|<~30).
// R23: mlp MROWS=2 (16 waves/CU); stats passes prefetch depth 3 (ring-4,
// fully unrolled -> static indices). All arithmetic bitwise unchanged.

// ---------------- Kernel 1: q = mlp_q(x), k = mlp_k(x) -> f16 ----------------
__global__ __launch_bounds__(256) void k_mlp(
    const float* __restrict__ x,
    const float* __restrict__ Wq1, const float* __restrict__ bq1,
    const float* __restrict__ Wq2, const float* __restrict__ bq2,
    const float* __restrict__ Wk1, const float* __restrict__ bk1,
    const float* __restrict__ Wk2, const float* __restrict__ bk2,
    _Float16* __restrict__ qo, _Float16* __restrict__ ko)
{
    __shared__ float xs[4][MROWS][FIN];
    __shared__ float hqs[4][MROWS][D];
    __shared__ float hks[4][MROWS][D];
    const int wave  = threadIdx.x >> 6;
    const int lane  = threadIdx.x & 63;
    const int rbase = (blockIdx.x * 4 + wave) * MROWS;

    #pragma unroll
    for (int r = 0; r < MROWS; ++r) {
        const float* xr = x + (size_t)(rbase + r) * FIN;
        xs[wave][r][lane]      = xr[lane];
        xs[wave][r][64 + lane] = xr[64 + lane];
        if (lane == 0) xs[wave][r][128] = xr[128];
    }
    __syncthreads();

    float aq[MROWS], ak[MROWS];
    #pragma unroll
    for (int r = 0; r < MROWS; ++r) { aq[r] = bq1[lane]; ak[r] = bk1[lane]; }
    for (int f = 0; f < FIN; ++f) {
        const float wq = Wq1[f * D + lane];
        const float wk = Wk1[f * D + lane];
        #pragma unroll
        for (int r = 0; r < MROWS; ++r) {
            const float xv = xs[wave][r][f];
            aq[r] = fmaf(xv, wq, aq[r]);
            ak[r] = fmaf(xv, wk, ak[r]);
        }
    }
    #pragma unroll
    for (int r = 0; r < MROWS; ++r) {
        hqs[wave][r][lane] = fmaxf(aq[r], 0.f);
        hks[wave][r][lane] = fmaxf(ak[r], 0.f);
    }
    __syncthreads();

    float oq[MROWS], ok[MROWS];
    #pragma unroll
    for (int r = 0; r < MROWS; ++r) { oq[r] = bq2[lane]; ok[r] = bk2[lane]; }
    for (int t = 0; t < D; ++t) {
        const float wq2 = Wq2[t * D + lane];
        const float wk2 = Wk2[t * D + lane];
        #pragma unroll
        for (int r = 0; r < MROWS; ++r) {
            oq[r] = fmaf(hqs[wave][r][t], wq2, oq[r]);
            ok[r] = fmaf(hks[wave][r][t], wk2, ok[r]);
        }
    }
    #pragma unroll
    for (int r = 0; r < MROWS; ++r) {
        qo[(size_t)(rbase + r) * D + lane] = (_Float16)oq[r];
        ko[(size_t)(rbase + r) * D + lane] = (_Float16)ok[r];
    }
}

// ---------------- Pass 1: raw row max -> mpart[SPLIT_S][N] (depth-3 prefetch) ----------------
__global__ __launch_bounds__(256) void k_max(
    const _Float16* __restrict__ q16, const _Float16* __restrict__ k16,
    float* __restrict__ mpart)
{
    const int tid  = threadIdx.x;
    const int wave = tid >> 6;
    const int lane = tid & 63;
    const int lr   = lane & 15;
    const int lg   = lane >> 4;
    const int i0   = blockIdx.x * BROWS + wave * 64;
    const int jbase = blockIdx.y * (N / SPLIT_S);

    f16x8 b[RG][2];
    #pragma unroll
    for (int rg = 0; rg < RG; ++rg) {
        b[rg][0] = *reinterpret_cast<const f16x8*>(&q16[(i0 + rg * 16 + lr) * D + 8 * lg]);
        b[rg][1] = *reinterpret_cast<const f16x8*>(&q16[(i0 + rg * 16 + lr) * D + 32 + 8 * lg]);
    }

    float mx[RG];
    #pragma unroll
    for (int rg = 0; rg < RG; ++rg) mx[rg] = -INFINITY;

    f16x8 a0[4], a1[4];
    #pragma unroll
    for (int s = 0; s < 3; ++s) {
        const int jr = jbase + s * 16;
        a0[s] = *reinterpret_cast<const f16x8*>(&k16[(jr + lr) * D + 8 * lg]);
        a1[s] = *reinterpret_cast<const f16x8*>(&k16[(jr + lr) * D + 32 + 8 * lg]);
    }

    #pragma unroll
    for (int s = 0; s < 16; ++s) {
        if (s + 3 < 16) {
            const int jr = jbase + (s + 3) * 16;
            a0[(s + 3) & 3] = *reinterpret_cast<const f16x8*>(&k16[(jr + lr) * D + 8 * lg]);
            a1[(s + 3) & 3] = *reinterpret_cast<const f16x8*>(&k16[(jr + lr) * D + 32 + 8 * lg]);
        }
        #pragma unroll
        for (int rg = 0; rg < RG; ++rg) {
            f32x4 acc = {0.f, 0.f, 0.f, 0.f};
            acc = MFMA16(a0[s & 3], b[rg][0], acc);
            acc = MFMA16(a1[s & 3], b[rg][1], acc);
            mx[rg] = fmaxf(mx[rg], fmaxf(fmaxf(acc[0], acc[1]), fmaxf(acc[2], acc[3])));
        }
    }

    #pragma unroll
    for (int rg = 0; rg < RG; ++rg) {
        mx[rg] = fmaxf(mx[rg], __shfl_xor(mx[rg], 16));
        mx[rg] = fmaxf(mx[rg], __shfl_xor(mx[rg], 32));
    }
    if (lane < 16) {
        #pragma unroll
        for (int rg = 0; rg < RG; ++rg)
            mpart[blockIdx.y * N + i0 + rg * 16 + lr] = mx[rg];
    }
}

// ---------------- Pass 2: Lpart[s][i] = sum_j exp2(s2_ij); depth-3 prefetch ----------------
__global__ __launch_bounds__(256) void k_sumL(
    const _Float16* __restrict__ q16, const _Float16* __restrict__ k16,
    const float* __restrict__ mpart, float* __restrict__ Lpart)
{
    const int tid  = threadIdx.x;
    const int wave = tid >> 6;
    const int lane = tid & 63;
    const int lr   = lane & 15;
    const int lg   = lane >> 4;
    const int i0   = blockIdx.x * BROWS + wave * 64;
    const int jbase = blockIdx.y * (N / SPLIT_S);

    __shared__ float rinv_s[N / SPLIT_S];   // 256 cols per slice
    {
        float m = mpart[jbase + tid];
        #pragma unroll
        for (int s = 1; s < SPLIT_S; ++s) m = fmaxf(m, mpart[s * N + jbase + tid]);
        rinv_s[tid] = TEMP * LOG2E / m;
    }

    f16x8 b[RG][2];
    #pragma unroll
    for (int rg = 0; rg < RG; ++rg) {
        b[rg][0] = *reinterpret_cast<const f16x8*>(&q16[(i0 + rg * 16 + lr) * D + 8 * lg]);
        b[rg][1] = *reinterpret_cast<const f16x8*>(&q16[(i0 + rg * 16 + lr) * D + 32 + 8 * lg]);
    }
    __syncthreads();

    float sm[RG];
    #pragma unroll
    for (int rg = 0; rg < RG; ++rg) sm[rg] = 0.f;

    f16x8 a0[4], a1[4];
    #pragma unroll
    for (int s = 0; s < 3; ++s) {
        const int jr = jbase + s * 16;
        a0[s] = *reinterpret_cast<const f16x8*>(&k16[(jr + lr) * D + 8 * lg]);
        a1[s] = *reinterpret_cast<const f16x8*>(&k16[(jr + lr) * D + 32 + 8 * lg]);
    }

    #pragma unroll
    for (int s = 0; s < 16; ++s) {
        if (s + 3 < 16) {
            const int jr = jbase + (s + 3) * 16;
            a0[(s + 3) & 3] = *reinterpret_cast<const f16x8*>(&k16[(jr + lr) * D + 8 * lg]);
            a1[(s + 3) & 3] = *reinterpret_cast<const f16x8*>(&k16[(jr + lr) * D + 32 + 8 * lg]);
        }
        const float4 r4 = *reinterpret_cast<const float4*>(&rinv_s[s * 16 + lg * 4]);
        #pragma unroll
        for (int rg = 0; rg < RG; ++rg) {
            f32x4 acc = {0.f, 0.f, 0.f, 0.f};
            acc = MFMA16(a0[s & 3], b[rg][0], acc);
            acc = MFMA16(a1[s & 3], b[rg][1], acc);
            sm[rg] += fast_exp2(acc[0] * r4.x) + fast_exp2(acc[1] * r4.y)
                    + fast_exp2(acc[2] * r4.z) + fast_exp2(acc[3] * r4.w);
        }
    }

    #pragma unroll
    for (int rg = 0; rg < RG; ++rg) {
        sm[rg] += __shfl_xor(sm[rg], 16);
        sm[rg] += __shfl_xor(sm[rg], 32);
    }
    if (lane < 16) {
        #pragma unroll
        for (int rg = 0; rg < RG; ++rg)
            Lpart[blockIdx.y * N + i0 + rg * 16 + lr] = sm[rg];
    }
}

// ---------------- Pass 3: paired line-completing PLAIN stores (R18-exact) ----------------
__global__ __launch_bounds__(256) void k_write(
    const _Float16* __restrict__ q16, const _Float16* __restrict__ k16,
    const float* __restrict__ mpart, const float* __restrict__ Lpart,
    float* __restrict__ out)
{
    const int tid  = threadIdx.x;
    const int wave = tid >> 6;
    const int lane = tid & 63;
    const int lr   = lane & 15;
    const int lg   = lane >> 4;
    const int i0b  = blockIdx.x * BROWS;
    const int i0   = i0b + wave * 64;
    const int jbase = blockIdx.y * (N / SPLIT_W);

    __shared__ float rinv_s[N / SPLIT_W];   // 256 cols per slice
    __shared__ float linv_s[BROWS];         // 256 rows per block
    {
        float m = mpart[jbase + tid];
        #pragma unroll
        for (int s = 1; s < SPLIT_S; ++s) m = fmaxf(m, mpart[s * N + jbase + tid]);
        rinv_s[tid] = TEMP * LOG2E / m;
        float L = Lpart[i0b + tid];
        #pragma unroll
        for (int s = 1; s < SPLIT_S; ++s) L += Lpart[s * N + i0b + tid];
        linv_s[tid] = 1.f / L;
    }

    f16x8 b[RG][2];
    #pragma unroll
    for (int rg = 0; rg < RG; ++rg) {
        b[rg][0] = *reinterpret_cast<const f16x8*>(&q16[(i0 + rg * 16 + lr) * D + 8 * lg]);
        b[rg][1] = *reinterpret_cast<const f16x8*>(&q16[(i0 + rg * 16 + lr) * D + 32 + 8 * lg]);
    }
    __syncthreads();

    float Lvi[RG];
    #pragma unroll
    for (int rg = 0; rg < RG; ++rg) Lvi[rg] = linv_s[wave * 64 + rg * 16 + lr];

    // pair loop: 8 pairs x 32 cols; a[buf][0,1]=sub0 frags, a[buf][2,3]=sub1 frags
    f16x8 a[2][4];
    a[0][0] = *reinterpret_cast<const f16x8*>(&k16[(jbase + lr) * D + 8 * lg]);
    a[0][1] = *reinterpret_cast<const f16x8*>(&k16[(jbase + lr) * D + 32 + 8 * lg]);
    a[0][2] = *reinterpret_cast<const f16x8*>(&k16[(jbase + 16 + lr) * D + 8 * lg]);
    a[0][3] = *reinterpret_cast<const f16x8*>(&k16[(jbase + 16 + lr) * D + 32 + 8 * lg]);

    #pragma unroll
    for (int s2 = 0; s2 < 8; ++s2) {
        const int p = s2 & 1;
        if (s2 + 1 < 8) {
            const int jn = jbase + (s2 + 1) * 32;
            a[1 - p][0] = *reinterpret_cast<const f16x8*>(&k16[(jn + lr) * D + 8 * lg]);
            a[1 - p][1] = *reinterpret_cast<const f16x8*>(&k16[(jn + lr) * D + 32 + 8 * lg]);
            a[1 - p][2] = *reinterpret_cast<const f16x8*>(&k16[(jn + 16 + lr) * D + 8 * lg]);
            a[1 - p][3] = *reinterpret_cast<const f16x8*>(&k16[(jn + 16 + lr) * D + 32 + 8 * lg]);
        }
        const int j0 = jbase + s2 * 32;
        const float4 r40 = *reinterpret_cast<const float4*>(&rinv_s[s2 * 32 + lg * 4]);
        const float4 r41 = *reinterpret_cast<const float4*>(&rinv_s[s2 * 32 + 16 + lg * 4]);
        #pragma unroll
        for (int rg = 0; rg < RG; ++rg) {
            f32x4 acc0 = {0.f, 0.f, 0.f, 0.f};
            acc0 = MFMA16(a[p][0], b[rg][0], acc0);
            acc0 = MFMA16(a[p][1], b[rg][1], acc0);
            f32x4 acc1 = {0.f, 0.f, 0.f, 0.f};
            acc1 = MFMA16(a[p][2], b[rg][0], acc1);
            acc1 = MFMA16(a[p][3], b[rg][1], acc1);
            float4 o0, o1;
            o0.x = fast_exp2(acc0[0] * r40.x) * Lvi[rg];
            o0.y = fast_exp2(acc0[1] * r40.y) * Lvi[rg];
            o0.z = fast_exp2(acc0[2] * r40.z) * Lvi[rg];
            o0.w = fast_exp2(acc0[3] * r40.w) * Lvi[rg];
            o1.x = fast_exp2(acc1[0] * r41.x) * Lvi[rg];
            o1.y = fast_exp2(acc1[1] * r41.y) * Lvi[rg];
            o1.z = fast_exp2(acc1[2] * r41.z) * Lvi[rg];
            o1.w = fast_exp2(acc1[3] * r41.w) * Lvi[rg];
            float* rowp = out + (size_t)(i0 + rg * 16 + lr) * N + j0;
            // back-to-back stores complete the 128B line (cols j0..j0+31)
            *reinterpret_cast<float4*>(rowp + lg * 4)      = o0;
            *reinterpret_cast<float4*>(rowp + 16 + lg * 4) = o1;
        }
    }
}

extern "C" void kernel_launch(void* const* d_in, const int* in_sizes, int n_in,
                              void* d_out, int out_size, void* d_ws, size_t ws_size,
                              hipStream_t stream)
{
    const float* x   = (const float*)d_in[0];
    const float* Wq1 = (const float*)d_in[1];
    const float* bq1 = (const float*)d_in[2];
    const float* Wq2 = (const float*)d_in[3];
    const float* bq2 = (const float*)d_in[4];
    const float* Wk1 = (const float*)d_in[5];
    const float* bk1 = (const float*)d_in[6];
    const float* Wk2 = (const float*)d_in[7];
    const float* bk2 = (const float*)d_in[8];

    float* out = (float*)d_out;

    _Float16* q16 = (_Float16*)d_ws;                       // 1 MB
    _Float16* k16 = q16 + (size_t)N * D;                   // 1 MB
    float* mpart  = (float*)(k16 + (size_t)N * D);         // SPLIT_S*N
    float* Lpart  = mpart + (size_t)SPLIT_S * N;           // SPLIT_S*N

    k_mlp  <<<N / (4 * MROWS), 256, 0, stream>>>(x, Wq1, bq1, Wq2, bq2, Wk1, bk1, Wk2, bk2, q16, k16);
    k_max  <<<dim3(N / BROWS, SPLIT_S), 256, 0, stream>>>(q16, k16, mpart);
    k_sumL <<<dim3(N / BROWS, SPLIT_S), 256, 0, stream>>>(q16, k16, mpart, Lpart);
    k_write<<<dim3(N / BROWS, SPLIT_W), 256, 0, stream>>>(q16, k16, mpart, Lpart, out);
}